// Round 1
// baseline (718.636 us; speedup 1.0000x reference)
//
#include <hip/hip_runtime.h>
#include <math.h>

#define DIM 64

// ---------------------------------------------------------------------------
// K1: hx = x @ W   (W is [in=64, out=64] row-major, hx[r][c] = sum_k x[r][k]*W[k][c])
// One wave (64 lanes) per row; lane = output column c. W staged in LDS (16 KB).
// x row shared across lanes via __shfl broadcast.
// ---------------------------------------------------------------------------
__global__ void gemm64_kernel(const float* __restrict__ x,
                              const float* __restrict__ W,
                              float* __restrict__ hx, int n) {
    __shared__ float Ws[DIM * DIM];
    for (int i = threadIdx.x; i < DIM * DIM; i += blockDim.x) Ws[i] = W[i];
    __syncthreads();

    const int lane = threadIdx.x & 63;
    const int wave = threadIdx.x >> 6;
    const int wpb  = blockDim.x >> 6;

    for (int row = blockIdx.x * wpb + wave; row < n; row += gridDim.x * wpb) {
        float xv = x[row * DIM + lane];
        float acc = 0.0f;
#pragma unroll
        for (int k = 0; k < DIM; ++k) {
            acc = fmaf(__shfl(xv, k, 64), Ws[k * DIM + lane], acc);
        }
        hx[row * DIM + lane] = acc;
    }
}

// ---------------------------------------------------------------------------
// K2: per-edge gather + fused edge scalar + scatter-add into out (accumulator)
// thread t -> edge e = t/64, dim d = t%64. Lanes of a wave cover all 64 dims
// of one edge: coalesced gather of hx[col], coalesced atomic scatter to out[row].
// ---------------------------------------------------------------------------
__global__ void edge_scatter_kernel(const int* __restrict__ ei,   // [2,E] int32
                                    const float* __restrict__ sw, // [E]
                                    const float* __restrict__ rep,// [N]
                                    const float* __restrict__ ns, // [N]
                                    const float* __restrict__ hx, // [N,64]
                                    float* __restrict__ out,      // [N,64] accum
                                    float* __restrict__ deg,      // [N]
                                    int E) {
    long long t = (long long)blockIdx.x * blockDim.x + threadIdx.x;
    int e = (int)(t >> 6);
    int d = (int)(t & 63);
    if (e >= E) return;

    int r = ei[e];
    int c = ei[E + e];

    float g    = rep[r] + rep[c];
    float gate = 1.0f / (1.0f + __expf(-g));
    float coef = sw[e] * gate * ns[c];

    float v = coef * hx[c * DIM + d];
    atomicAdd(&out[r * DIM + d], v);
    if (d == 0) atomicAdd(&deg[r], 1.0f);
}

// ---------------------------------------------------------------------------
// K3: finalize. self = x @ W_self computed on the fly (W_self in LDS),
// out = leaky_relu(out/(deg+1e-6) + sigmoid(rep)*self), in-place on d_out.
// ---------------------------------------------------------------------------
__global__ void finalize_kernel(const float* __restrict__ x,
                                const float* __restrict__ Wself,
                                const float* __restrict__ rep,
                                const float* __restrict__ deg,
                                float* __restrict__ out, int n) {
    __shared__ float Ws[DIM * DIM];
    for (int i = threadIdx.x; i < DIM * DIM; i += blockDim.x) Ws[i] = Wself[i];
    __syncthreads();

    const int lane = threadIdx.x & 63;
    const int wave = threadIdx.x >> 6;
    const int wpb  = blockDim.x >> 6;

    for (int row = blockIdx.x * wpb + wave; row < n; row += gridDim.x * wpb) {
        float xv = x[row * DIM + lane];
        float acc = 0.0f;
#pragma unroll
        for (int k = 0; k < DIM; ++k) {
            acc = fmaf(__shfl(xv, k, 64), Ws[k * DIM + lane], acc);
        }
        float srep = 1.0f / (1.0f + __expf(-rep[row]));
        float v = out[row * DIM + lane] / (deg[row] + 1e-6f) + srep * acc;
        out[row * DIM + lane] = (v > 0.0f) ? v : 0.01f * v;
    }
}

// ---------------------------------------------------------------------------
// kernel_launch
// inputs: 0=x [N*64 f32], 1=edge_index [2*E int], 2=sim_weight [E f32],
//         3=rep [N f32], 4=node_signal [N f32], 5=W [64*64 f32], 6=W_self [64*64 f32]
// out: [N*64 f32]
// ws: hx (N*64 f32) + deg (N f32)
// ---------------------------------------------------------------------------
extern "C" void kernel_launch(void* const* d_in, const int* in_sizes, int n_in,
                              void* d_out, int out_size, void* d_ws, size_t ws_size,
                              hipStream_t stream) {
    const float* x     = (const float*)d_in[0];
    const int*   ei    = (const int*)d_in[1];
    const float* sw    = (const float*)d_in[2];
    const float* rep   = (const float*)d_in[3];
    const float* ns    = (const float*)d_in[4];
    const float* W     = (const float*)d_in[5];
    const float* Wself = (const float*)d_in[6];

    const int n = in_sizes[0] / DIM;   // 100000
    const int E = in_sizes[2];         // 1600000

    float* out = (float*)d_out;
    float* hx  = (float*)d_ws;                       // n*64 floats
    float* deg = (float*)d_ws + (size_t)n * DIM;     // n floats

    // zero the accumulators (d_out is used as the segment-sum accumulator)
    hipMemsetAsync(d_out, 0, (size_t)out_size * sizeof(float), stream);
    hipMemsetAsync(deg, 0, (size_t)n * sizeof(float), stream);

    // K1: hx = x @ W
    {
        const int block = 256;               // 4 waves
        const int wpb = block / 64;
        int grid = (n + wpb - 1) / wpb;
        gemm64_kernel<<<grid, block, 0, stream>>>(x, W, hx, n);
    }

    // K2: edge scatter
    {
        const int block = 256;
        long long total = (long long)E * DIM;
        long long grid = (total + block - 1) / block;
        edge_scatter_kernel<<<(int)grid, block, 0, stream>>>(ei, sw, rep, ns, hx,
                                                             out, deg, E);
    }

    // K3: finalize
    {
        const int block = 256;
        const int wpb = block / 64;
        int grid = (n + wpb - 1) / wpb;
        finalize_kernel<<<grid, block, 0, stream>>>(x, Wself, rep, deg, out, n);
    }
}

// Round 2
// 607.619 us; speedup vs baseline: 1.1827x; 1.1827x over previous
//
#include <hip/hip_runtime.h>
#include <math.h>

#define DIM 64

// ---------------------------------------------------------------------------
// K1: hx = x @ W. One wave per row, lane = output column, W in LDS.
// ---------------------------------------------------------------------------
__global__ void gemm64_kernel(const float* __restrict__ x,
                              const float* __restrict__ W,
                              float* __restrict__ hx, int n) {
    __shared__ float Ws[DIM * DIM];
    for (int i = threadIdx.x; i < DIM * DIM; i += blockDim.x) Ws[i] = W[i];
    __syncthreads();

    const int lane = threadIdx.x & 63;
    const int wave = threadIdx.x >> 6;
    const int wpb  = blockDim.x >> 6;

    for (int row = blockIdx.x * wpb + wave; row < n; row += gridDim.x * wpb) {
        float xv = x[row * DIM + lane];
        float acc = 0.0f;
#pragma unroll
        for (int k = 0; k < DIM; ++k) {
            acc = fmaf(__shfl(xv, k, 64), Ws[k * DIM + lane], acc);
        }
        hx[row * DIM + lane] = acc;
    }
}

// ---------------------------------------------------------------------------
// CSR build step 1: histogram of destination rows (int atomics, cheap).
// ---------------------------------------------------------------------------
__global__ void hist_kernel(const int* __restrict__ ei, int* __restrict__ cnt, int E) {
    int e = blockIdx.x * blockDim.x + threadIdx.x;
    if (e < E) atomicAdd(&cnt[ei[e]], 1);
}

// ---------------------------------------------------------------------------
// CSR build step 2a: per-tile (1024) exclusive scan; tile totals to blk_sums.
// ---------------------------------------------------------------------------
__global__ void scan_tile_kernel(const int* __restrict__ cnt,
                                 int* __restrict__ row_ptr,   // local-exclusive for now
                                 int* __restrict__ blk_sums, int n) {
    __shared__ int wsum[16];
    const int tid = threadIdx.x;
    const int lane = tid & 63;
    const int wv = tid >> 6;          // 0..15
    int i = blockIdx.x * 1024 + tid;
    int v = (i < n) ? cnt[i] : 0;
    int s = v;
#pragma unroll
    for (int off = 1; off < 64; off <<= 1) {
        int t = __shfl_up(s, off, 64);
        if (lane >= off) s += t;
    }
    if (lane == 63) wsum[wv] = s;     // wave totals
    __syncthreads();
    if (wv == 0 && lane < 16) {
        int w = wsum[lane], sw = w;
#pragma unroll
        for (int off = 1; off < 16; off <<= 1) {
            int t = __shfl_up(sw, off, 16);
            if (lane >= off) sw += t;
        }
        wsum[lane] = sw - w;          // exclusive prefix of wave sums
    }
    __syncthreads();
    int excl = wsum[wv] + (s - v);
    if (i < n) row_ptr[i] = excl;
    if (tid == 1023) blk_sums[blockIdx.x] = wsum[15] + s;   // tile total
}

// ---------------------------------------------------------------------------
// CSR build step 2b: single-block scan of tile totals (nb <= 256).
// ---------------------------------------------------------------------------
__global__ void scan_blk_kernel(int* __restrict__ blk_sums, int nb) {
    __shared__ int sh[256];
    const int tid = threadIdx.x;
    sh[tid] = (tid < nb) ? blk_sums[tid] : 0;
    __syncthreads();
    for (int off = 1; off < 256; off <<= 1) {
        int t = 0;
        if (tid >= off) t = sh[tid - off];
        __syncthreads();
        if (tid >= off) sh[tid] += t;
        __syncthreads();
    }
    if (tid < nb) blk_sums[tid] = (tid == 0) ? 0 : sh[tid - 1];  // exclusive
}

// ---------------------------------------------------------------------------
// CSR build step 2c: add tile offsets; produce row_ptr and cursor copies.
// ---------------------------------------------------------------------------
__global__ void scan_add_kernel(int* __restrict__ row_ptr,
                                const int* __restrict__ blk_sums,
                                int* __restrict__ cursor, int n, int E) {
    int i = blockIdx.x * 1024 + threadIdx.x;
    if (i < n) {
        int v = row_ptr[i] + blk_sums[blockIdx.x];
        row_ptr[i] = v;
        cursor[i]  = v;
    }
    if (blockIdx.x == 0 && threadIdx.x == 0) row_ptr[n] = E;
}

// ---------------------------------------------------------------------------
// CSR build step 3: scatter edges into buckets; fuse edge-scalar computation.
// csr[slot] = (col bit-cast, coef)
// ---------------------------------------------------------------------------
__global__ void fill_kernel(const int* __restrict__ ei,
                            const float* __restrict__ sw,
                            const float* __restrict__ rep,
                            const float* __restrict__ ns,
                            int* __restrict__ cursor,
                            float2* __restrict__ csr, int E) {
    int e = blockIdx.x * blockDim.x + threadIdx.x;
    if (e >= E) return;
    int r = ei[e];
    int c = ei[E + e];
    float gate = 1.0f / (1.0f + __expf(-(rep[r] + rep[c])));
    float coef = sw[e] * gate * ns[c];
    int slot = atomicAdd(&cursor[r], 1);
    csr[slot] = make_float2(__int_as_float(c), coef);
}

// ---------------------------------------------------------------------------
// K-final: gather + normalize + self-term + leaky-relu, one wave per node.
// Single coalesced 256 B write per node; hx gathers served by L2/L3.
// ---------------------------------------------------------------------------
__global__ void gather_finalize_kernel(const float* __restrict__ x,
                                       const float* __restrict__ Wself,
                                       const float* __restrict__ rep,
                                       const int* __restrict__ row_ptr,
                                       const float2* __restrict__ csr,
                                       const float* __restrict__ hx,
                                       float* __restrict__ out, int n) {
    __shared__ float Ws[DIM * DIM];
    for (int i = threadIdx.x; i < DIM * DIM; i += blockDim.x) Ws[i] = Wself[i];
    __syncthreads();

    const int lane = threadIdx.x & 63;
    const int wave = threadIdx.x >> 6;
    const int wpb  = blockDim.x >> 6;

    for (int row = blockIdx.x * wpb + wave; row < n; row += gridDim.x * wpb) {
        const int beg = row_ptr[row];
        const int end = row_ptr[row + 1];

        float acc = 0.0f;
        int p = beg;
        for (; p + 1 < end; p += 2) {       // 2x unroll for MLP
            float2 a0 = csr[p];
            float2 a1 = csr[p + 1];
            int c0 = __float_as_int(a0.x);
            int c1 = __float_as_int(a1.x);
            float h0 = hx[(size_t)c0 * DIM + lane];
            float h1 = hx[(size_t)c1 * DIM + lane];
            acc = fmaf(a0.y, h0, acc);
            acc = fmaf(a1.y, h1, acc);
        }
        if (p < end) {
            float2 a0 = csr[p];
            int c0 = __float_as_int(a0.x);
            acc = fmaf(a0.y, hx[(size_t)c0 * DIM + lane], acc);
        }

        float deg = (float)(end - beg);

        // self = (x @ W_self)[row][lane]
        float xv = x[row * DIM + lane];
        float self = 0.0f;
#pragma unroll
        for (int k = 0; k < DIM; ++k) {
            self = fmaf(__shfl(xv, k, 64), Ws[k * DIM + lane], self);
        }
        float srep = 1.0f / (1.0f + __expf(-rep[row]));
        float v = acc / (deg + 1e-6f) + srep * self;
        out[row * DIM + lane] = (v > 0.0f) ? v : 0.01f * v;
    }
}

// ---------------------------------------------------------------------------
// Fallback (small ws): original atomic-scatter path.
// ---------------------------------------------------------------------------
__global__ void edge_scatter_kernel(const int* __restrict__ ei,
                                    const float* __restrict__ sw,
                                    const float* __restrict__ rep,
                                    const float* __restrict__ ns,
                                    const float* __restrict__ hx,
                                    float* __restrict__ out,
                                    float* __restrict__ deg, int E) {
    long long t = (long long)blockIdx.x * blockDim.x + threadIdx.x;
    int e = (int)(t >> 6);
    int d = (int)(t & 63);
    if (e >= E) return;
    int r = ei[e];
    int c = ei[E + e];
    float gate = 1.0f / (1.0f + __expf(-(rep[r] + rep[c])));
    float coef = sw[e] * gate * ns[c];
    atomicAdd(&out[r * DIM + d], coef * hx[c * DIM + d]);
    if (d == 0) atomicAdd(&deg[r], 1.0f);
}

__global__ void finalize_kernel(const float* __restrict__ x,
                                const float* __restrict__ Wself,
                                const float* __restrict__ rep,
                                const float* __restrict__ deg,
                                float* __restrict__ out, int n) {
    __shared__ float Ws[DIM * DIM];
    for (int i = threadIdx.x; i < DIM * DIM; i += blockDim.x) Ws[i] = Wself[i];
    __syncthreads();
    const int lane = threadIdx.x & 63;
    const int wave = threadIdx.x >> 6;
    const int wpb  = blockDim.x >> 6;
    for (int row = blockIdx.x * wpb + wave; row < n; row += gridDim.x * wpb) {
        float xv = x[row * DIM + lane];
        float self = 0.0f;
#pragma unroll
        for (int k = 0; k < DIM; ++k)
            self = fmaf(__shfl(xv, k, 64), Ws[k * DIM + lane], self);
        float srep = 1.0f / (1.0f + __expf(-rep[row]));
        float v = out[row * DIM + lane] / (deg[row] + 1e-6f) + srep * self;
        out[row * DIM + lane] = (v > 0.0f) ? v : 0.01f * v;
    }
}

// ---------------------------------------------------------------------------
extern "C" void kernel_launch(void* const* d_in, const int* in_sizes, int n_in,
                              void* d_out, int out_size, void* d_ws, size_t ws_size,
                              hipStream_t stream) {
    const float* x     = (const float*)d_in[0];
    const int*   ei    = (const int*)d_in[1];
    const float* sw    = (const float*)d_in[2];
    const float* rep   = (const float*)d_in[3];
    const float* ns    = (const float*)d_in[4];
    const float* W     = (const float*)d_in[5];
    const float* Wself = (const float*)d_in[6];

    const int n = in_sizes[0] / DIM;   // 100000
    const int E = in_sizes[2];         // 1600000

    float* out = (float*)d_out;
    char*  ws  = (char*)d_ws;

    // ws layout (all offsets 8B-aligned where needed)
    size_t off = 0;
    float*  hx       = (float*)(ws + off);  off += (size_t)n * DIM * 4;   // 25.6 MB
    float2* csr      = (float2*)(ws + off); off += (size_t)E * 8;         // 12.8 MB
    int*    cnt      = (int*)(ws + off);    off += (size_t)n * 4;
    int*    row_ptr  = (int*)(ws + off);    off += (size_t)(n + 1) * 4;
    int*    cursor   = (int*)(ws + off);    off += (size_t)n * 4;
    int*    blk_sums = (int*)(ws + off);    off += 256 * 4;
    const size_t need = off;

    const int nb = (n + 1023) / 1024;   // scan tiles (<=256 assumed: n<=262144)

    if (ws_size >= need && nb <= 256) {
        // --- CSR gather path ---
        hipMemsetAsync(cnt, 0, (size_t)n * sizeof(int), stream);

        {   // hx = x @ W
            const int block = 256, wpb = block / 64;
            gemm64_kernel<<<(n + wpb - 1) / wpb, block, 0, stream>>>(x, W, hx, n);
        }
        hist_kernel<<<(E + 255) / 256, 256, 0, stream>>>(ei, cnt, E);
        scan_tile_kernel<<<nb, 1024, 0, stream>>>(cnt, row_ptr, blk_sums, n);
        scan_blk_kernel<<<1, 256, 0, stream>>>(blk_sums, nb);
        scan_add_kernel<<<nb, 1024, 0, stream>>>(row_ptr, blk_sums, cursor, n, E);
        fill_kernel<<<(E + 255) / 256, 256, 0, stream>>>(ei, sw, rep, ns, cursor, csr, E);
        {   // gather + finalize
            const int block = 256, wpb = block / 64;
            gather_finalize_kernel<<<(n + wpb - 1) / wpb, block, 0, stream>>>(
                x, Wself, rep, row_ptr, csr, hx, out, n);
        }
    } else {
        // --- fallback: atomic scatter path ---
        float* hx2 = (float*)ws;
        float* deg = (float*)ws + (size_t)n * DIM;
        hipMemsetAsync(d_out, 0, (size_t)out_size * sizeof(float), stream);
        hipMemsetAsync(deg, 0, (size_t)n * sizeof(float), stream);
        {
            const int block = 256, wpb = block / 64;
            gemm64_kernel<<<(n + wpb - 1) / wpb, block, 0, stream>>>(x, W, hx2, n);
        }
        {
            long long total = (long long)E * DIM;
            edge_scatter_kernel<<<(int)((total + 255) / 256), 256, 0, stream>>>(
                ei, sw, rep, ns, hx2, out, deg, E);
        }
        {
            const int block = 256, wpb = block / 64;
            finalize_kernel<<<(n + wpb - 1) / wpb, block, 0, stream>>>(
                x, Wself, rep, deg, out, n);
        }
    }
}

// Round 3
// 397.651 us; speedup vs baseline: 1.8072x; 1.5280x over previous
//
#include <hip/hip_runtime.h>
#include <math.h>

#define DIM 64

static __device__ inline unsigned short f32_to_bf16(float f) {
    unsigned u = __float_as_uint(f);
    u += 0x7FFFu + ((u >> 16) & 1u);   // round-to-nearest-even
    return (unsigned short)(u >> 16);
}
static __device__ inline float bf16_to_f32(unsigned short h) {
    return __uint_as_float((unsigned)h << 16);
}

// ---------------------------------------------------------------------------
// K1: dual GEMM. hxb = bf16(x @ W); self_pre = sigmoid(rep) * (x @ W_self).
// One wave per row, lane = output column. Both weight mats in LDS (32 KB).
// ---------------------------------------------------------------------------
__global__ void gemm_dual_kernel(const float* __restrict__ x,
                                 const float* __restrict__ W,
                                 const float* __restrict__ Wself,
                                 const float* __restrict__ rep,
                                 unsigned short* __restrict__ hxb,
                                 float* __restrict__ self_pre, int n) {
    __shared__ float Ws[DIM * DIM];
    __shared__ float Vs[DIM * DIM];
    for (int i = threadIdx.x; i < DIM * DIM; i += blockDim.x) {
        Ws[i] = W[i];
        Vs[i] = Wself[i];
    }
    __syncthreads();

    const int lane = threadIdx.x & 63;
    const int wave = threadIdx.x >> 6;
    const int wpb  = blockDim.x >> 6;

    for (int row = blockIdx.x * wpb + wave; row < n; row += gridDim.x * wpb) {
        float xv = x[(size_t)row * DIM + lane];
        float a1 = 0.0f, a2 = 0.0f;
#pragma unroll
        for (int k = 0; k < DIM; ++k) {
            float b = __shfl(xv, k, 64);
            a1 = fmaf(b, Ws[k * DIM + lane], a1);
            a2 = fmaf(b, Vs[k * DIM + lane], a2);
        }
        hxb[(size_t)row * DIM + lane] = f32_to_bf16(a1);
        float srep = 1.0f / (1.0f + __expf(-rep[row]));
        self_pre[(size_t)row * DIM + lane] = srep * a2;
    }
}

// ---------------------------------------------------------------------------
// CSR build: histogram -> scan -> fill (coef fused into fill).
// ---------------------------------------------------------------------------
__global__ void hist_kernel(const int* __restrict__ ei, int* __restrict__ cnt, int E) {
    int e = blockIdx.x * blockDim.x + threadIdx.x;
    if (e < E) atomicAdd(&cnt[ei[e]], 1);
}

__global__ void scan_tile_kernel(const int* __restrict__ cnt,
                                 int* __restrict__ row_ptr,
                                 int* __restrict__ blk_sums, int n) {
    __shared__ int wsum[16];
    const int tid = threadIdx.x;
    const int lane = tid & 63;
    const int wv = tid >> 6;
    int i = blockIdx.x * 1024 + tid;
    int v = (i < n) ? cnt[i] : 0;
    int s = v;
#pragma unroll
    for (int off = 1; off < 64; off <<= 1) {
        int t = __shfl_up(s, off, 64);
        if (lane >= off) s += t;
    }
    if (lane == 63) wsum[wv] = s;
    __syncthreads();
    if (wv == 0 && lane < 16) {
        int w = wsum[lane], sw = w;
#pragma unroll
        for (int off = 1; off < 16; off <<= 1) {
            int t = __shfl_up(sw, off, 16);
            if (lane >= off) sw += t;
        }
        wsum[lane] = sw - w;
    }
    __syncthreads();
    int excl = wsum[wv] + (s - v);
    if (i < n) row_ptr[i] = excl;
    if (tid == 1023) blk_sums[blockIdx.x] = wsum[15] + s;
}

__global__ void scan_blk_kernel(int* __restrict__ blk_sums, int nb) {
    __shared__ int sh[256];
    const int tid = threadIdx.x;
    sh[tid] = (tid < nb) ? blk_sums[tid] : 0;
    __syncthreads();
    for (int off = 1; off < 256; off <<= 1) {
        int t = 0;
        if (tid >= off) t = sh[tid - off];
        __syncthreads();
        if (tid >= off) sh[tid] += t;
        __syncthreads();
    }
    if (tid < nb) blk_sums[tid] = (tid == 0) ? 0 : sh[tid - 1];
}

__global__ void scan_add_kernel(int* __restrict__ row_ptr,
                                const int* __restrict__ blk_sums,
                                int* __restrict__ cursor, int n, int E) {
    int i = blockIdx.x * 1024 + threadIdx.x;
    if (i < n) {
        int v = row_ptr[i] + blk_sums[blockIdx.x];
        row_ptr[i] = v;
        cursor[i]  = v;
    }
    if (blockIdx.x == 0 && threadIdx.x == 0) row_ptr[n] = E;
}

__global__ void fill_kernel(const int* __restrict__ ei,
                            const float* __restrict__ sw,
                            const float* __restrict__ rep,
                            const float* __restrict__ ns,
                            int* __restrict__ cursor,
                            float2* __restrict__ csr, int E) {
    int e = blockIdx.x * blockDim.x + threadIdx.x;
    if (e >= E) return;
    int r = ei[e];
    int c = ei[E + e];
    float gate = 1.0f / (1.0f + __expf(-(rep[r] + rep[c])));
    float coef = sw[e] * gate * ns[c];
    int slot = atomicAdd(&cursor[r], 1);
    csr[slot] = make_float2(__int_as_float(c), coef);
}

// ---------------------------------------------------------------------------
// K-final: pure gather + FMA + epilogue. One wave per row.
// csr entries for up to 64 edges fetched with ONE coalesced lane-distributed
// load, broadcast by shfl -> 8 independent hx gathers in flight per chunk.
// ---------------------------------------------------------------------------
template<int K>
__device__ inline void gather_k(int j, int cv, float wv,
                                const unsigned short* __restrict__ hxb,
                                int lane, float& acc) {
    int c[K]; float w[K]; unsigned short h[K];
#pragma unroll
    for (int i = 0; i < K; ++i) {
        c[i] = __shfl(cv, j + i, 64);
        w[i] = __shfl(wv, j + i, 64);
    }
#pragma unroll
    for (int i = 0; i < K; ++i) h[i] = hxb[(size_t)c[i] * DIM + lane];
#pragma unroll
    for (int i = 0; i < K; ++i) acc = fmaf(w[i], bf16_to_f32(h[i]), acc);
}

__global__ void gather_finalize_kernel(const int* __restrict__ row_ptr,
                                       const float2* __restrict__ csr,
                                       const unsigned short* __restrict__ hxb,
                                       const float* __restrict__ self_pre,
                                       float* __restrict__ out, int n) {
    const int lane = threadIdx.x & 63;
    const int wave = threadIdx.x >> 6;
    const int wpb  = blockDim.x >> 6;

    for (int row = blockIdx.x * wpb + wave; row < n; row += gridDim.x * wpb) {
        const int beg = row_ptr[row];
        const int end = row_ptr[row + 1];
        float acc = 0.0f;

        for (int base = beg; base < end; base += 64) {
            int m = end - base;
            if (m > 64) m = 64;
            float2 av = csr[base + (lane < m ? lane : 0)];
            int   cv = __float_as_int(av.x);
            float wv = av.y;

            int j = 0;
            for (; j + 8 <= m; j += 8) gather_k<8>(j, cv, wv, hxb, lane, acc);
            if (j + 4 <= m) { gather_k<4>(j, cv, wv, hxb, lane, acc); j += 4; }
            if (j + 2 <= m) { gather_k<2>(j, cv, wv, hxb, lane, acc); j += 2; }
            if (j < m)      { gather_k<1>(j, cv, wv, hxb, lane, acc); }
        }

        float deg = (float)(end - beg);
        float v = acc / (deg + 1e-6f) + self_pre[(size_t)row * DIM + lane];
        out[(size_t)row * DIM + lane] = (v > 0.0f) ? v : 0.01f * v;
    }
}

// ---------------------------------------------------------------------------
// Fallback (small ws): atomic-scatter path (f32 hx).
// ---------------------------------------------------------------------------
__global__ void gemm64_kernel(const float* __restrict__ x,
                              const float* __restrict__ W,
                              float* __restrict__ hx, int n) {
    __shared__ float Ws[DIM * DIM];
    for (int i = threadIdx.x; i < DIM * DIM; i += blockDim.x) Ws[i] = W[i];
    __syncthreads();
    const int lane = threadIdx.x & 63;
    const int wave = threadIdx.x >> 6;
    const int wpb  = blockDim.x >> 6;
    for (int row = blockIdx.x * wpb + wave; row < n; row += gridDim.x * wpb) {
        float xv = x[(size_t)row * DIM + lane];
        float acc = 0.0f;
#pragma unroll
        for (int k = 0; k < DIM; ++k)
            acc = fmaf(__shfl(xv, k, 64), Ws[k * DIM + lane], acc);
        hx[(size_t)row * DIM + lane] = acc;
    }
}

__global__ void edge_scatter_kernel(const int* __restrict__ ei,
                                    const float* __restrict__ sw,
                                    const float* __restrict__ rep,
                                    const float* __restrict__ ns,
                                    const float* __restrict__ hx,
                                    float* __restrict__ out,
                                    float* __restrict__ deg, int E) {
    long long t = (long long)blockIdx.x * blockDim.x + threadIdx.x;
    int e = (int)(t >> 6);
    int d = (int)(t & 63);
    if (e >= E) return;
    int r = ei[e];
    int c = ei[E + e];
    float gate = 1.0f / (1.0f + __expf(-(rep[r] + rep[c])));
    float coef = sw[e] * gate * ns[c];
    atomicAdd(&out[(size_t)r * DIM + d], coef * hx[(size_t)c * DIM + d]);
    if (d == 0) atomicAdd(&deg[r], 1.0f);
}

__global__ void finalize_kernel(const float* __restrict__ x,
                                const float* __restrict__ Wself,
                                const float* __restrict__ rep,
                                const float* __restrict__ deg,
                                float* __restrict__ out, int n) {
    __shared__ float Ws[DIM * DIM];
    for (int i = threadIdx.x; i < DIM * DIM; i += blockDim.x) Ws[i] = Wself[i];
    __syncthreads();
    const int lane = threadIdx.x & 63;
    const int wave = threadIdx.x >> 6;
    const int wpb  = blockDim.x >> 6;
    for (int row = blockIdx.x * wpb + wave; row < n; row += gridDim.x * wpb) {
        float xv = x[(size_t)row * DIM + lane];
        float self = 0.0f;
#pragma unroll
        for (int k = 0; k < DIM; ++k)
            self = fmaf(__shfl(xv, k, 64), Ws[k * DIM + lane], self);
        float srep = 1.0f / (1.0f + __expf(-rep[row]));
        float v = out[(size_t)row * DIM + lane] / (deg[row] + 1e-6f) + srep * self;
        out[(size_t)row * DIM + lane] = (v > 0.0f) ? v : 0.01f * v;
    }
}

// ---------------------------------------------------------------------------
extern "C" void kernel_launch(void* const* d_in, const int* in_sizes, int n_in,
                              void* d_out, int out_size, void* d_ws, size_t ws_size,
                              hipStream_t stream) {
    const float* x     = (const float*)d_in[0];
    const int*   ei    = (const int*)d_in[1];
    const float* sw    = (const float*)d_in[2];
    const float* rep   = (const float*)d_in[3];
    const float* ns    = (const float*)d_in[4];
    const float* W     = (const float*)d_in[5];
    const float* Wself = (const float*)d_in[6];

    const int n = in_sizes[0] / DIM;   // 100000
    const int E = in_sizes[2];         // 1600000

    float* out = (float*)d_out;
    char*  ws  = (char*)d_ws;

    size_t off = 0;
    unsigned short* hxb = (unsigned short*)(ws + off); off += (size_t)n * DIM * 2;  // 12.8 MB
    float*  self_pre = (float*)(ws + off);  off += (size_t)n * DIM * 4;             // 25.6 MB
    float2* csr      = (float2*)(ws + off); off += (size_t)E * 8;                   // 12.8 MB
    int*    cnt      = (int*)(ws + off);    off += (size_t)n * 4;
    int*    row_ptr  = (int*)(ws + off);    off += (size_t)(n + 1) * 4;
    int*    cursor   = (int*)(ws + off);    off += (size_t)n * 4;
    int*    blk_sums = (int*)(ws + off);    off += 256 * 4;
    const size_t need = off;

    const int nb = (n + 1023) / 1024;

    if (ws_size >= need && nb <= 256) {
        hipMemsetAsync(cnt, 0, (size_t)n * sizeof(int), stream);

        {
            const int block = 256, wpb = block / 64;
            gemm_dual_kernel<<<(n + wpb - 1) / wpb, block, 0, stream>>>(
                x, W, Wself, rep, hxb, self_pre, n);
        }
        hist_kernel<<<(E + 255) / 256, 256, 0, stream>>>(ei, cnt, E);
        scan_tile_kernel<<<nb, 1024, 0, stream>>>(cnt, row_ptr, blk_sums, n);
        scan_blk_kernel<<<1, 256, 0, stream>>>(blk_sums, nb);
        scan_add_kernel<<<nb, 1024, 0, stream>>>(row_ptr, blk_sums, cursor, n, E);
        fill_kernel<<<(E + 255) / 256, 256, 0, stream>>>(ei, sw, rep, ns, cursor, csr, E);
        {
            const int block = 256, wpb = block / 64;
            gather_finalize_kernel<<<(n + wpb - 1) / wpb, block, 0, stream>>>(
                row_ptr, csr, hxb, self_pre, out, n);
        }
    } else {
        float* hx2 = (float*)ws;
        float* deg = (float*)ws + (size_t)n * DIM;
        hipMemsetAsync(d_out, 0, (size_t)out_size * sizeof(float), stream);
        hipMemsetAsync(deg, 0, (size_t)n * sizeof(float), stream);
        {
            const int block = 256, wpb = block / 64;
            gemm64_kernel<<<(n + wpb - 1) / wpb, block, 0, stream>>>(x, W, hx2, n);
        }
        {
            long long total = (long long)E * DIM;
            edge_scatter_kernel<<<(int)((total + 255) / 256), 256, 0, stream>>>(
                ei, sw, rep, ns, hx2, out, deg, E);
        }
        {
            const int block = 256, wpb = block / 64;
            finalize_kernel<<<(n + wpb - 1) / wpb, block, 0, stream>>>(
                x, Wself, rep, deg, out, n);
        }
    }
}

// Round 4
// 224.816 us; speedup vs baseline: 3.1966x; 1.7688x over previous
//
#include <hip/hip_runtime.h>
#include <math.h>

#define DIM 64

static __device__ inline unsigned short f32_to_bf16(float f) {
    unsigned u = __float_as_uint(f);
    u += 0x7FFFu + ((u >> 16) & 1u);   // round-to-nearest-even
    return (unsigned short)(u >> 16);
}
static __device__ inline float bf16_to_f32(unsigned short h) {
    return __uint_as_float((unsigned)h << 16);
}

// ---------------------------------------------------------------------------
// K1: tiled dual GEMM. hxb = bf16(x @ W); self_pre = sigmoid(rep)*(x @ W_self).
// Block = 256 threads = 64-row tile. x tile + W + W_self staged in LDS.
// Thread computes 4 rows x 4 cols of BOTH products: per k, 2x ds_read_b128
// (W,V) + 4 broadcast b32 (x) -> 32 FMAs. FMA-pipe bound, no shfl chain.
// ---------------------------------------------------------------------------
__global__ __launch_bounds__(256) void gemm_dual_tiled(
        const float* __restrict__ x,
        const float* __restrict__ W,
        const float* __restrict__ Wself,
        const float* __restrict__ rep,
        unsigned short* __restrict__ hxb,
        float* __restrict__ self_pre, int n) {
    __shared__ float xs[64][68];           // padded: 272 B/row, 16B aligned
    __shared__ float Ws[64][64];
    __shared__ float Vs[64][64];

    const int t = threadIdx.x;
    const int row0 = blockIdx.x * 64;

    // stage W and W_self (1024 float4 each)
    {
        const float4* W4 = (const float4*)W;
        const float4* V4 = (const float4*)Wself;
        float4* Ws4 = (float4*)&Ws[0][0];
        float4* Vs4 = (float4*)&Vs[0][0];
        for (int i = t; i < 1024; i += 256) { Ws4[i] = W4[i]; Vs4[i] = V4[i]; }
    }
    // stage x tile (1024 float4), zero-pad rows beyond n
    for (int i = t; i < 1024; i += 256) {
        int r = i >> 4, c4 = i & 15;
        float4 v = make_float4(0.f, 0.f, 0.f, 0.f);
        if (row0 + r < n) v = ((const float4*)x)[(size_t)(row0 + r) * 16 + c4];
        *(float4*)&xs[r][c4 * 4] = v;
    }
    __syncthreads();

    const int rg = t >> 4;           // 0..15 row group
    const int r0 = rg * 4;
    const int c0 = (t & 15) * 4;     // 0..60 col start

    float4 a1[4], a2[4];
#pragma unroll
    for (int j = 0; j < 4; ++j) {
        a1[j] = make_float4(0.f, 0.f, 0.f, 0.f);
        a2[j] = make_float4(0.f, 0.f, 0.f, 0.f);
    }

#pragma unroll 8
    for (int k = 0; k < 64; ++k) {
        float4 wv = *(const float4*)&Ws[k][c0];
        float4 vv = *(const float4*)&Vs[k][c0];
        float xk0 = xs[r0 + 0][k];
        float xk1 = xs[r0 + 1][k];
        float xk2 = xs[r0 + 2][k];
        float xk3 = xs[r0 + 3][k];

        a1[0].x = fmaf(xk0, wv.x, a1[0].x); a1[0].y = fmaf(xk0, wv.y, a1[0].y);
        a1[0].z = fmaf(xk0, wv.z, a1[0].z); a1[0].w = fmaf(xk0, wv.w, a1[0].w);
        a1[1].x = fmaf(xk1, wv.x, a1[1].x); a1[1].y = fmaf(xk1, wv.y, a1[1].y);
        a1[1].z = fmaf(xk1, wv.z, a1[1].z); a1[1].w = fmaf(xk1, wv.w, a1[1].w);
        a1[2].x = fmaf(xk2, wv.x, a1[2].x); a1[2].y = fmaf(xk2, wv.y, a1[2].y);
        a1[2].z = fmaf(xk2, wv.z, a1[2].z); a1[2].w = fmaf(xk2, wv.w, a1[2].w);
        a1[3].x = fmaf(xk3, wv.x, a1[3].x); a1[3].y = fmaf(xk3, wv.y, a1[3].y);
        a1[3].z = fmaf(xk3, wv.z, a1[3].z); a1[3].w = fmaf(xk3, wv.w, a1[3].w);

        a2[0].x = fmaf(xk0, vv.x, a2[0].x); a2[0].y = fmaf(xk0, vv.y, a2[0].y);
        a2[0].z = fmaf(xk0, vv.z, a2[0].z); a2[0].w = fmaf(xk0, vv.w, a2[0].w);
        a2[1].x = fmaf(xk1, vv.x, a2[1].x); a2[1].y = fmaf(xk1, vv.y, a2[1].y);
        a2[1].z = fmaf(xk1, vv.z, a2[1].z); a2[1].w = fmaf(xk1, vv.w, a2[1].w);
        a2[2].x = fmaf(xk2, vv.x, a2[2].x); a2[2].y = fmaf(xk2, vv.y, a2[2].y);
        a2[2].z = fmaf(xk2, vv.z, a2[2].z); a2[2].w = fmaf(xk2, vv.w, a2[2].w);
        a2[3].x = fmaf(xk3, vv.x, a2[3].x); a2[3].y = fmaf(xk3, vv.y, a2[3].y);
        a2[3].z = fmaf(xk3, vv.z, a2[3].z); a2[3].w = fmaf(xk3, vv.w, a2[3].w);
    }

#pragma unroll
    for (int j = 0; j < 4; ++j) {
        int row = row0 + r0 + j;
        if (row >= n) break;
        // hxb: 4 bf16 packed into 8B
        ushort4 hb;
        hb.x = f32_to_bf16(a1[j].x); hb.y = f32_to_bf16(a1[j].y);
        hb.z = f32_to_bf16(a1[j].z); hb.w = f32_to_bf16(a1[j].w);
        *(ushort4*)&hxb[(size_t)row * DIM + c0] = hb;
        float srep = 1.0f / (1.0f + __expf(-rep[row]));
        float4 sp = make_float4(srep * a2[j].x, srep * a2[j].y,
                                srep * a2[j].z, srep * a2[j].w);
        *(float4*)&self_pre[(size_t)row * DIM + c0] = sp;
    }
}

// ---------------------------------------------------------------------------
// CSR build: histogram -> scan -> fill (coef fused into fill).
// ---------------------------------------------------------------------------
__global__ void hist_kernel(const int* __restrict__ ei, int* __restrict__ cnt, int E) {
    int e = blockIdx.x * blockDim.x + threadIdx.x;
    if (e < E) atomicAdd(&cnt[ei[e]], 1);
}

__global__ void scan_tile_kernel(const int* __restrict__ cnt,
                                 int* __restrict__ row_ptr,
                                 int* __restrict__ blk_sums, int n) {
    __shared__ int wsum[16];
    const int tid = threadIdx.x;
    const int lane = tid & 63;
    const int wv = tid >> 6;
    int i = blockIdx.x * 1024 + tid;
    int v = (i < n) ? cnt[i] : 0;
    int s = v;
#pragma unroll
    for (int off = 1; off < 64; off <<= 1) {
        int t = __shfl_up(s, off, 64);
        if (lane >= off) s += t;
    }
    if (lane == 63) wsum[wv] = s;
    __syncthreads();
    if (wv == 0 && lane < 16) {
        int w = wsum[lane], sw = w;
#pragma unroll
        for (int off = 1; off < 16; off <<= 1) {
            int t = __shfl_up(sw, off, 16);
            if (lane >= off) sw += t;
        }
        wsum[lane] = sw - w;
    }
    __syncthreads();
    int excl = wsum[wv] + (s - v);
    if (i < n) row_ptr[i] = excl;
    if (tid == 1023) blk_sums[blockIdx.x] = wsum[15] + s;
}

__global__ void scan_blk_kernel(int* __restrict__ blk_sums, int nb) {
    __shared__ int sh[256];
    const int tid = threadIdx.x;
    sh[tid] = (tid < nb) ? blk_sums[tid] : 0;
    __syncthreads();
    for (int off = 1; off < 256; off <<= 1) {
        int t = 0;
        if (tid >= off) t = sh[tid - off];
        __syncthreads();
        if (tid >= off) sh[tid] += t;
        __syncthreads();
    }
    if (tid < nb) blk_sums[tid] = (tid == 0) ? 0 : sh[tid - 1];
}

__global__ void scan_add_kernel(int* __restrict__ row_ptr,
                                const int* __restrict__ blk_sums,
                                int* __restrict__ cursor, int n, int E) {
    int i = blockIdx.x * 1024 + threadIdx.x;
    if (i < n) {
        int v = row_ptr[i] + blk_sums[blockIdx.x];
        row_ptr[i] = v;
        cursor[i]  = v;
    }
    if (blockIdx.x == 0 && threadIdx.x == 0) row_ptr[n] = E;
}

__global__ void fill_kernel(const int* __restrict__ ei,
                            const float* __restrict__ sw,
                            const float* __restrict__ rep,
                            const float* __restrict__ ns,
                            int* __restrict__ cursor,
                            float2* __restrict__ csr, int E) {
    int e = blockIdx.x * blockDim.x + threadIdx.x;
    if (e >= E) return;
    int r = ei[e];
    int c = ei[E + e];
    float gate = 1.0f / (1.0f + __expf(-(rep[r] + rep[c])));
    float coef = sw[e] * gate * ns[c];
    int slot = atomicAdd(&cursor[r], 1);
    csr[slot] = make_float2(__int_as_float(c), coef);
}

// ---------------------------------------------------------------------------
// K-final: pure gather + FMA + epilogue. One wave per row; csr entries for 64
// edges fetched with one coalesced lane load, broadcast by shfl -> 8
// independent bf16 hx gathers in flight per chunk.
// ---------------------------------------------------------------------------
template<int K>
__device__ inline void gather_k(int j, int cv, float wv,
                                const unsigned short* __restrict__ hxb,
                                int lane, float& acc) {
    int c[K]; float w[K]; unsigned short h[K];
#pragma unroll
    for (int i = 0; i < K; ++i) {
        c[i] = __shfl(cv, j + i, 64);
        w[i] = __shfl(wv, j + i, 64);
    }
#pragma unroll
    for (int i = 0; i < K; ++i) h[i] = hxb[(size_t)c[i] * DIM + lane];
#pragma unroll
    for (int i = 0; i < K; ++i) acc = fmaf(w[i], bf16_to_f32(h[i]), acc);
}

__global__ void gather_finalize_kernel(const int* __restrict__ row_ptr,
                                       const float2* __restrict__ csr,
                                       const unsigned short* __restrict__ hxb,
                                       const float* __restrict__ self_pre,
                                       float* __restrict__ out, int n) {
    const int lane = threadIdx.x & 63;
    const int wave = threadIdx.x >> 6;
    const int wpb  = blockDim.x >> 6;

    for (int row = blockIdx.x * wpb + wave; row < n; row += gridDim.x * wpb) {
        const int beg = row_ptr[row];
        const int end = row_ptr[row + 1];
        float acc = 0.0f;

        for (int base = beg; base < end; base += 64) {
            int m = end - base;
            if (m > 64) m = 64;
            float2 av = csr[base + (lane < m ? lane : 0)];
            int   cv = __float_as_int(av.x);
            float wv = av.y;

            int j = 0;
            for (; j + 8 <= m; j += 8) gather_k<8>(j, cv, wv, hxb, lane, acc);
            if (j + 4 <= m) { gather_k<4>(j, cv, wv, hxb, lane, acc); j += 4; }
            if (j + 2 <= m) { gather_k<2>(j, cv, wv, hxb, lane, acc); j += 2; }
            if (j < m)      { gather_k<1>(j, cv, wv, hxb, lane, acc); }
        }

        float deg = (float)(end - beg);
        float v = acc / (deg + 1e-6f) + self_pre[(size_t)row * DIM + lane];
        out[(size_t)row * DIM + lane] = (v > 0.0f) ? v : 0.01f * v;
    }
}

// ---------------------------------------------------------------------------
// Fallback (small ws): atomic-scatter path (f32 hx).
// ---------------------------------------------------------------------------
__global__ void gemm64_kernel(const float* __restrict__ x,
                              const float* __restrict__ W,
                              float* __restrict__ hx, int n) {
    __shared__ float Ws[DIM * DIM];
    for (int i = threadIdx.x; i < DIM * DIM; i += blockDim.x) Ws[i] = W[i];
    __syncthreads();
    const int lane = threadIdx.x & 63;
    const int wave = threadIdx.x >> 6;
    const int wpb  = blockDim.x >> 6;
    for (int row = blockIdx.x * wpb + wave; row < n; row += gridDim.x * wpb) {
        float xv = x[(size_t)row * DIM + lane];
        float acc = 0.0f;
#pragma unroll
        for (int k = 0; k < DIM; ++k)
            acc = fmaf(__shfl(xv, k, 64), Ws[k * DIM + lane], acc);
        hx[(size_t)row * DIM + lane] = acc;
    }
}

__global__ void edge_scatter_kernel(const int* __restrict__ ei,
                                    const float* __restrict__ sw,
                                    const float* __restrict__ rep,
                                    const float* __restrict__ ns,
                                    const float* __restrict__ hx,
                                    float* __restrict__ out,
                                    float* __restrict__ deg, int E) {
    long long t = (long long)blockIdx.x * blockDim.x + threadIdx.x;
    int e = (int)(t >> 6);
    int d = (int)(t & 63);
    if (e >= E) return;
    int r = ei[e];
    int c = ei[E + e];
    float gate = 1.0f / (1.0f + __expf(-(rep[r] + rep[c])));
    float coef = sw[e] * gate * ns[c];
    atomicAdd(&out[(size_t)r * DIM + d], coef * hx[(size_t)c * DIM + d]);
    if (d == 0) atomicAdd(&deg[r], 1.0f);
}

__global__ void finalize_kernel(const float* __restrict__ x,
                                const float* __restrict__ Wself,
                                const float* __restrict__ rep,
                                const float* __restrict__ deg,
                                float* __restrict__ out, int n) {
    __shared__ float Ws[DIM * DIM];
    for (int i = threadIdx.x; i < DIM * DIM; i += blockDim.x) Ws[i] = Wself[i];
    __syncthreads();
    const int lane = threadIdx.x & 63;
    const int wave = threadIdx.x >> 6;
    const int wpb  = blockDim.x >> 6;
    for (int row = blockIdx.x * wpb + wave; row < n; row += gridDim.x * wpb) {
        float xv = x[(size_t)row * DIM + lane];
        float self = 0.0f;
#pragma unroll
        for (int k = 0; k < DIM; ++k)
            self = fmaf(__shfl(xv, k, 64), Ws[k * DIM + lane], self);
        float srep = 1.0f / (1.0f + __expf(-rep[row]));
        float v = out[(size_t)row * DIM + lane] / (deg[row] + 1e-6f) + srep * self;
        out[(size_t)row * DIM + lane] = (v > 0.0f) ? v : 0.01f * v;
    }
}

// ---------------------------------------------------------------------------
extern "C" void kernel_launch(void* const* d_in, const int* in_sizes, int n_in,
                              void* d_out, int out_size, void* d_ws, size_t ws_size,
                              hipStream_t stream) {
    const float* x     = (const float*)d_in[0];
    const int*   ei    = (const int*)d_in[1];
    const float* sw    = (const float*)d_in[2];
    const float* rep   = (const float*)d_in[3];
    const float* ns    = (const float*)d_in[4];
    const float* W     = (const float*)d_in[5];
    const float* Wself = (const float*)d_in[6];

    const int n = in_sizes[0] / DIM;   // 100000
    const int E = in_sizes[2];         // 1600000

    float* out = (float*)d_out;
    char*  ws  = (char*)d_ws;

    size_t off = 0;
    unsigned short* hxb = (unsigned short*)(ws + off); off += (size_t)n * DIM * 2;  // 12.8 MB
    float*  self_pre = (float*)(ws + off);  off += (size_t)n * DIM * 4;             // 25.6 MB
    float2* csr      = (float2*)(ws + off); off += (size_t)E * 8;                   // 12.8 MB
    int*    cnt      = (int*)(ws + off);    off += (size_t)n * 4;
    int*    row_ptr  = (int*)(ws + off);    off += (size_t)(n + 1) * 4;
    int*    cursor   = (int*)(ws + off);    off += (size_t)n * 4;
    int*    blk_sums = (int*)(ws + off);    off += 256 * 4;
    const size_t need = off;

    const int nb = (n + 1023) / 1024;

    if (ws_size >= need && nb <= 256) {
        hipMemsetAsync(cnt, 0, (size_t)n * sizeof(int), stream);

        gemm_dual_tiled<<<(n + 63) / 64, 256, 0, stream>>>(
            x, W, Wself, rep, hxb, self_pre, n);

        hist_kernel<<<(E + 255) / 256, 256, 0, stream>>>(ei, cnt, E);
        scan_tile_kernel<<<nb, 1024, 0, stream>>>(cnt, row_ptr, blk_sums, n);
        scan_blk_kernel<<<1, 256, 0, stream>>>(blk_sums, nb);
        scan_add_kernel<<<nb, 1024, 0, stream>>>(row_ptr, blk_sums, cursor, n, E);
        fill_kernel<<<(E + 255) / 256, 256, 0, stream>>>(ei, sw, rep, ns, cursor, csr, E);
        {
            const int block = 256, wpb = block / 64;
            gather_finalize_kernel<<<(n + wpb - 1) / wpb, block, 0, stream>>>(
                row_ptr, csr, hxb, self_pre, out, n);
        }
    } else {
        float* hx2 = (float*)ws;
        float* deg = (float*)ws + (size_t)n * DIM;
        hipMemsetAsync(d_out, 0, (size_t)out_size * sizeof(float), stream);
        hipMemsetAsync(deg, 0, (size_t)n * sizeof(float), stream);
        {
            const int block = 256, wpb = block / 64;
            gemm64_kernel<<<(n + wpb - 1) / wpb, block, 0, stream>>>(x, W, hx2, n);
        }
        {
            long long total = (long long)E * DIM;
            edge_scatter_kernel<<<(int)((total + 255) / 256), 256, 0, stream>>>(
                ei, sw, rep, ns, hx2, out, deg, E);
        }
        {
            const int block = 256, wpb = block / 64;
            finalize_kernel<<<(n + wpb - 1) / wpb, block, 0, stream>>>(
                x, Wself, rep, deg, out, n);
        }
    }
}